// Round 6
// baseline (73.263 us; speedup 1.0000x reference)
//
#include <hip/hip_runtime.h>

// Ordered product of 4,194,304 (+1 repeat) 2x2 float32 matrices; out = e0^T * M.
// float4 = row-major 2x2: (x y ; z w).
//
// Two-kernel tree reduction. Phase 1: 4096 blocks x 256 threads, ONE int4 of
// tokens per thread -> perfectly coalesced (lane i reads base+16i, minimal
// line transactions; 32B/64B-strided layouts measurably regress: R2 vs R3/R4).
// Gathers hit an LDS-staged copy of the 2 KB table (R5: -2.2us vs L1 gathers).

#define T_TOKENS 4194304
#define TPB      256
#define TOKS     4                                   // tokens per thread
#define BLOCKS   (T_TOKENS / (TPB * TOKS))           // 4096

__device__ __forceinline__ float4 mm(const float4 A, const float4 B) {
    float4 C;
    C.x = fmaf(A.x, B.x, A.y * B.z);
    C.y = fmaf(A.x, B.y, A.y * B.w);
    C.z = fmaf(A.z, B.x, A.w * B.z);
    C.w = fmaf(A.z, B.y, A.w * B.w);
    return C;
}

// Ordered wave reduce via shfl_down: after round s, lane j (j % 2s == 0) holds
// the product of segment [j, j+2s); lane 0 ends with the ordered wave product
// (left operand = lower lane = earlier segment; non-commutative safe).
__device__ __forceinline__ float4 wave_reduce_mm(float4 m) {
    #pragma unroll
    for (int s = 1; s < 64; s <<= 1) {
        float4 o;
        o.x = __shfl_down(m.x, s, 64);
        o.y = __shfl_down(m.y, s, 64);
        o.z = __shfl_down(m.z, s, 64);
        o.w = __shfl_down(m.w, s, 64);
        m = mm(m, o);
    }
    return m;
}

__global__ __launch_bounds__(TPB) void scan_phase1(const int4* __restrict__ tok4,
                                                   const float4* __restrict__ ls,
                                                   float4* __restrict__ partials) {
    __shared__ float4 s_ls[128];          // 2 KB staged transition table
    __shared__ float4 sm[4];

    const int tid = threadIdx.x;
    if (tid < 128) s_ls[tid] = ls[tid];
    __syncthreads();

    const int4 t = tok4[blockIdx.x * TPB + tid];   // perfectly coalesced 16 B/lane

    float4 m = s_ls[t.x];                 // ds_read_b128 gathers
    m = mm(m, s_ls[t.y]);
    m = mm(m, s_ls[t.z]);
    m = mm(m, s_ls[t.w]);

    m = wave_reduce_mm(m);                // lane 0 of each wave: wave product

    if ((tid & 63) == 0) sm[tid >> 6] = m;
    __syncthreads();
    if (tid == 0)
        partials[blockIdx.x] = mm(mm(sm[0], sm[1]), mm(sm[2], sm[3]));
}

// Phase 2: one block reduces 4096 partials in order (16 consecutive per
// thread), applies the doubled last-token matrix, writes row 0 (v0 = [1,0]).
__global__ __launch_bounds__(TPB) void scan_phase2(const float4* __restrict__ partials,
                                                   const int* __restrict__ tokens,
                                                   const float4* __restrict__ ls,
                                                   float* __restrict__ out) {
    const int tid = threadIdx.x;
    float4 m = partials[tid * 16];
    #pragma unroll
    for (int k = 1; k < 16; ++k)
        m = mm(m, partials[tid * 16 + k]);

    m = wave_reduce_mm(m);

    __shared__ float4 sf[4];
    if ((tid & 63) == 0) sf[tid >> 6] = m;
    __syncthreads();
    if (tid == 0) {
        float4 M = mm(mm(sf[0], sf[1]), mm(sf[2], sf[3]));
        M = mm(M, ls[tokens[T_TOKENS - 1]]);   // last token applied twice
        out[0] = M.x;
        out[1] = M.y;
    }
}

extern "C" void kernel_launch(void* const* d_in, const int* in_sizes, int n_in,
                              void* d_out, int out_size, void* d_ws, size_t ws_size,
                              hipStream_t stream) {
    const int*    tokens = (const int*)d_in[0];     // (T,) int32
    const float4* ls     = (const float4*)d_in[1];  // (128,2,2) f32 == 128 x float4
    float*  out      = (float*)d_out;               // 2 floats
    float4* partials = (float4*)d_ws;               // 4096 * 16 B = 64 KB scratch

    scan_phase1<<<BLOCKS, TPB, 0, stream>>>((const int4*)tokens, ls, partials);
    scan_phase2<<<1, TPB, 0, stream>>>(partials, tokens, ls, out);
}

// Round 7
// 68.320 us; speedup vs baseline: 1.0724x; 1.0724x over previous
//
#include <hip/hip_runtime.h>

// Ordered product of 4,194,304 (+1 repeat) 2x2 float32 matrices; out = e0^T * M.
// float4 = row-major 2x2: (x y ; z w).
//
// Two-kernel tree reduction. Phase 1: 1024 blocks x 512 threads, 8 contiguous
// tokens/thread (two int4 loads, R5's proven layout), gathers from an
// LDS-staged 2 KB table. Wave reduction uses DPP row_shr for rounds 1/2/4/8
// (VALU-latency cross-lane, no DS pipe) and ds_swizzle-xor for rounds 16/32.

#define T_TOKENS 4194304
#define TPB      512
#define TOKS     8                                   // tokens per thread
#define BLOCKS   (T_TOKENS / (TPB * TOKS))           // 1024

__device__ __forceinline__ float4 mm(const float4 A, const float4 B) {
    float4 C;
    C.x = fmaf(A.x, B.x, A.y * B.z);
    C.y = fmaf(A.x, B.y, A.y * B.w);
    C.z = fmaf(A.z, B.x, A.w * B.z);
    C.w = fmaf(A.z, B.y, A.w * B.w);
    return C;
}

// lane i <- lane i+N within each 16-lane DPP row (row_shr:N). Lanes whose
// source crosses the row keep their own value (old=src, bound_ctrl=false);
// the reduction tree never consumes those lanes at that round.
template <int N>
__device__ __forceinline__ float4 dpp_shr4(const float4 m) {
    float4 o;
    o.x = __int_as_float(__builtin_amdgcn_update_dpp(
        __float_as_int(m.x), __float_as_int(m.x), 0x110 | N, 0xF, 0xF, false));
    o.y = __int_as_float(__builtin_amdgcn_update_dpp(
        __float_as_int(m.y), __float_as_int(m.y), 0x110 | N, 0xF, 0xF, false));
    o.z = __int_as_float(__builtin_amdgcn_update_dpp(
        __float_as_int(m.z), __float_as_int(m.z), 0x110 | N, 0xF, 0xF, false));
    o.w = __int_as_float(__builtin_amdgcn_update_dpp(
        __float_as_int(m.w), __float_as_int(m.w), 0x110 | N, 0xF, 0xF, false));
    return o;
}

// lane i <- lane i^XMASK via ds_swizzle (BitMode: offset = xor<<10 | 0x1F).
// For consuming lanes j aligned to 2*XMASK, j^XMASK == j+XMASK (shfl_down).
template <int XMASK>
__device__ __forceinline__ float4 swz_xor4(const float4 m) {
    constexpr int OFF = (XMASK << 10) | 0x1F;
    float4 o;
    o.x = __int_as_float(__builtin_amdgcn_ds_swizzle(__float_as_int(m.x), OFF));
    o.y = __int_as_float(__builtin_amdgcn_ds_swizzle(__float_as_int(m.y), OFF));
    o.z = __int_as_float(__builtin_amdgcn_ds_swizzle(__float_as_int(m.z), OFF));
    o.w = __int_as_float(__builtin_amdgcn_ds_swizzle(__float_as_int(m.w), OFF));
    return o;
}

// Ordered wave reduce (left operand = lower lane = earlier tokens): after
// round s, lane j (j % 2s == 0) holds the product of segment [j, j+2s).
// Lane 0 ends with the full ordered wave product.
__device__ __forceinline__ float4 wave_reduce_mm(float4 m) {
    m = mm(m, dpp_shr4<1>(m));
    m = mm(m, dpp_shr4<2>(m));
    m = mm(m, dpp_shr4<4>(m));
    m = mm(m, dpp_shr4<8>(m));
    m = mm(m, swz_xor4<16>(m));
    m = mm(m, swz_xor4<32>(m));
    return m;
}

// Phase 1: 1024 blocks x 512 threads (8 waves), 8 tokens/thread.
__global__ __launch_bounds__(TPB) void scan_phase1(const int4* __restrict__ tok4,
                                                   const float4* __restrict__ ls,
                                                   float4* __restrict__ partials) {
    __shared__ float4 s_ls[128];          // 2 KB staged transition table
    __shared__ float4 sm[8];

    const int tid = threadIdx.x;
    if (tid < 128) s_ls[tid] = ls[tid];
    __syncthreads();

    const int g  = blockIdx.x * TPB + tid;
    const int4 a = tok4[2 * g];
    const int4 b = tok4[2 * g + 1];

    float4 m = s_ls[a.x];                 // ds_read_b128 gathers
    m = mm(m, s_ls[a.y]);
    m = mm(m, s_ls[a.z]);
    m = mm(m, s_ls[a.w]);
    m = mm(m, s_ls[b.x]);
    m = mm(m, s_ls[b.y]);
    m = mm(m, s_ls[b.z]);
    m = mm(m, s_ls[b.w]);

    m = wave_reduce_mm(m);                // lane 0 of each wave: wave product

    if ((tid & 63) == 0) sm[tid >> 6] = m;
    __syncthreads();
    if (tid == 0) {
        const float4 q01 = mm(sm[0], sm[1]);
        const float4 q23 = mm(sm[2], sm[3]);
        const float4 q45 = mm(sm[4], sm[5]);
        const float4 q67 = mm(sm[6], sm[7]);
        partials[blockIdx.x] = mm(mm(q01, q23), mm(q45, q67));
    }
}

// Phase 2: one 256-thread block reduces 1024 partials in order (4 consecutive
// per thread), applies the doubled last-token matrix, writes row 0 (v0=[1,0]).
__global__ __launch_bounds__(256) void scan_phase2(const float4* __restrict__ partials,
                                                   const int* __restrict__ tokens,
                                                   const float4* __restrict__ ls,
                                                   float* __restrict__ out) {
    const int tid = threadIdx.x;
    float4 m = partials[tid * 4];
    #pragma unroll
    for (int k = 1; k < 4; ++k)
        m = mm(m, partials[tid * 4 + k]);

    m = wave_reduce_mm(m);

    __shared__ float4 sf[4];
    if ((tid & 63) == 0) sf[tid >> 6] = m;
    __syncthreads();
    if (tid == 0) {
        float4 M = mm(mm(sf[0], sf[1]), mm(sf[2], sf[3]));
        M = mm(M, ls[tokens[T_TOKENS - 1]]);   // last token applied twice
        out[0] = M.x;
        out[1] = M.y;
    }
}

extern "C" void kernel_launch(void* const* d_in, const int* in_sizes, int n_in,
                              void* d_out, int out_size, void* d_ws, size_t ws_size,
                              hipStream_t stream) {
    const int*    tokens = (const int*)d_in[0];     // (T,) int32
    const float4* ls     = (const float4*)d_in[1];  // (128,2,2) f32 == 128 x float4
    float*  out      = (float*)d_out;               // 2 floats
    float4* partials = (float4*)d_ws;               // 1024 * 16 B = 16 KB scratch

    scan_phase1<<<BLOCKS, TPB, 0, stream>>>((const int4*)tokens, ls, partials);
    scan_phase2<<<1, 256, 0, stream>>>(partials, tokens, ls, out);
}